// Round 3
// baseline (1081.299 us; speedup 1.0000x reference)
//
#include <hip/hip_runtime.h>
#include <hip/hip_bf16.h>

#define N_NODES 10000
#define N_EDGES 320000
#define F_IN_D 100
#define H1_D 200
#define H2_D 150
#define HID_D 100
#define OUT_D 12

#define GEMV_BLOCKS 2000
#define GEMV_THREADS 256
// total gemv threads = 512000; stride*4 = 2,048,000 ≡ 0 (mod 100) -> fixed j0 per thread
// stride 512,000 ≡ 0 (mod 25) -> x row index advances by exactly 20480 per iteration
static_assert((GEMV_BLOCKS * GEMV_THREADS * 4) % 100 == 0, "j0 must be loop-invariant");
static_assert((GEMV_BLOCKS * GEMV_THREADS) % 25 == 0, "x index increment must be exact");

__global__ void zero_kernel(int* __restrict__ a, int* __restrict__ b, int n) {
    int i = blockIdx.x * blockDim.x + threadIdx.x;
    if (i < n) { a[i] = 0; b[i] = 0; }
}

__global__ void deg_kernel(const int* __restrict__ edges, int* __restrict__ counts) {
    int e = blockIdx.x * blockDim.x + threadIdx.x;
    if (e < N_EDGES) {
        atomicAdd(&counts[edges[N_EDGES + e]], 1);   // dst row
    }
}

// single-block scan over counts -> row_ptr (exclusive prefix at [i], total at [N])
__global__ void scan_kernel(const int* __restrict__ counts, int* __restrict__ row_ptr) {
    __shared__ int tile[256];
    __shared__ int carry_s;
    if (threadIdx.x == 0) { carry_s = 0; row_ptr[0] = 0; }
    __syncthreads();
    for (int base = 0; base < N_NODES; base += 256) {
        int i = base + threadIdx.x;
        int v = (i < N_NODES) ? counts[i] : 0;
        tile[threadIdx.x] = v;
        __syncthreads();
        for (int off = 1; off < 256; off <<= 1) {
            int t = (threadIdx.x >= off) ? tile[threadIdx.x - off] : 0;
            __syncthreads();
            tile[threadIdx.x] += t;
            __syncthreads();
        }
        if (i < N_NODES) row_ptr[i + 1] = carry_s + tile[threadIdx.x];
        __syncthreads();
        if (threadIdx.x == 0) carry_s += tile[255];
        __syncthreads();
    }
}

__global__ void dinv_kernel(const int* __restrict__ counts, float* __restrict__ dinv) {
    int i = blockIdx.x * blockDim.x + threadIdx.x;
    if (i < N_NODES) dinv[i] = 1.0f / sqrtf((float)(counts[i] + 1));  // +1 self-loop
}

__global__ void fill_kernel(const int* __restrict__ edges, const int* __restrict__ row_ptr,
                            int* __restrict__ wofs, int* __restrict__ col) {
    int e = blockIdx.x * blockDim.x + threadIdx.x;
    if (e < N_EDGES) {
        int s = edges[e];             // src
        int d = edges[N_EDGES + e];   // dst
        int pos = row_ptr[d] + atomicAdd(&wofs[d], 1);
        col[pos] = s;
    }
}

// h = X @ W ; X [N,K] row-major, W [K,M] row-major. ROWS node-rows per block.
template<int K, int M, int ROWS>
__global__ __launch_bounds__(256) void gemm_kernel(const float* __restrict__ X,
                                                   const float* __restrict__ W,
                                                   float* __restrict__ h) {
    __shared__ float xs[ROWS * K];
    int i0 = blockIdx.x * ROWS;
    for (int idx = threadIdx.x; idx < ROWS * K; idx += blockDim.x)
        xs[idx] = X[i0 * K + idx];
    __syncthreads();
    int j = threadIdx.x;
    if (j < M) {
        float acc[ROWS];
        #pragma unroll
        for (int r = 0; r < ROWS; ++r) acc[r] = 0.0f;
        for (int k = 0; k < K; ++k) {
            float w = W[k * M + j];
            #pragma unroll
            for (int r = 0; r < ROWS; ++r)
                acc[r] = fmaf(xs[r * K + k], w, acc[r]);
        }
        #pragma unroll
        for (int r = 0; r < ROWS; ++r)
            h[(i0 + r) * M + j] = acc[r];
    }
}

// xout[i,j] = relu( dinv_i*( dinv_i*h[i,j] + sum_e dinv[src_e]*h[src_e,j] ) + b[j] )
template<int F>
__global__ __launch_bounds__(256) void agg_kernel(const float* __restrict__ h,
                                                  const float* __restrict__ dinv,
                                                  const int* __restrict__ row_ptr,
                                                  const int* __restrict__ col,
                                                  const float* __restrict__ b,
                                                  float* __restrict__ xout) {
    int i = blockIdx.x;
    int j = threadIdx.x;
    if (j >= F) return;
    float di = dinv[i];
    float acc = di * h[i * F + j];            // self-loop (x dinv_i at the end -> dinv_i^2)
    int e0 = row_ptr[i], e1 = row_ptr[i + 1];
    for (int e = e0; e < e1; ++e) {
        int s = col[e];                        // block-uniform -> scalar load
        acc = fmaf(dinv[s], h[s * F + j], acc);
    }
    float v = fmaf(di, acc, b[j]);
    xout[i * F + j] = fmaxf(v, 0.0f);
}

// y1_partial[block][j] = sum over this block's share of  x[k]*Wl1[k,j]
__global__ __launch_bounds__(GEMV_THREADS) void gemv_kernel(const float4* __restrict__ W4,
                                                            const float* __restrict__ x,
                                                            float* __restrict__ partials) {
    const int M4 = (N_NODES * H2_D * HID_D) / 4;   // 37,500,000 float4s
    const int STRIDE4 = GEMV_BLOCKS * GEMV_THREADS;
    int gtid = blockIdx.x * GEMV_THREADS + threadIdx.x;
    int j0 = (gtid * 4) % 100;                      // fixed across iterations
    int xk = gtid / 25;                             // advances by 20480 each iter (exact)
    float a0 = 0.f, a1 = 0.f, a2 = 0.f, a3 = 0.f;
    for (int idx4 = gtid; idx4 < M4; idx4 += STRIDE4, xk += STRIDE4 / 25) {
        float4 w = W4[idx4];
        float xv = x[xk];
        a0 = fmaf(w.x, xv, a0);
        a1 = fmaf(w.y, xv, a1);
        a2 = fmaf(w.z, xv, a2);
        a3 = fmaf(w.w, xv, a3);
    }
    __shared__ float ly[100];
    if (threadIdx.x < 100) ly[threadIdx.x] = 0.0f;
    __syncthreads();
    atomicAdd(&ly[j0 + 0], a0);
    atomicAdd(&ly[j0 + 1], a1);
    atomicAdd(&ly[j0 + 2], a2);
    atomicAdd(&ly[j0 + 3], a3);
    __syncthreads();
    if (threadIdx.x < 100) partials[blockIdx.x * 100 + threadIdx.x] = ly[threadIdx.x];
}

// reduce partials -> y1 = relu(.+bl1) -> out = sigmoid(y1 @ Wl2 + bl2)
__global__ __launch_bounds__(1024) void head_kernel(const float* __restrict__ partials,
                                                    const float* __restrict__ bl1,
                                                    const float* __restrict__ Wl2,
                                                    const float* __restrict__ bl2,
                                                    float* __restrict__ out) {
    __shared__ float s[1000];
    __shared__ float y[100];
    int t = threadIdx.x;
    if (t < 1000) {
        int g = t / 100, j = t % 100;
        float acc = 0.0f;
        for (int p = g; p < GEMV_BLOCKS; p += 10)
            acc += partials[p * 100 + j];
        s[t] = acc;
    }
    __syncthreads();
    if (t < 100) {
        float v = 0.0f;
        #pragma unroll
        for (int g = 0; g < 10; ++g) v += s[g * 100 + t];
        v += bl1[t];
        y[t] = fmaxf(v, 0.0f);
    }
    __syncthreads();
    if (t < OUT_D) {
        float acc = bl2[t];
        for (int k = 0; k < 100; ++k)
            acc = fmaf(y[k], Wl2[k * OUT_D + t], acc);
        out[t] = 1.0f / (1.0f + expf(-acc));
    }
}

extern "C" void kernel_launch(void* const* d_in, const int* in_sizes, int n_in,
                              void* d_out, int out_size, void* d_ws, size_t ws_size,
                              hipStream_t stream) {
    const float* nodes = (const float*)d_in[0];
    const int*   edges = (const int*)d_in[1];
    const float* W1    = (const float*)d_in[2];
    const float* b1    = (const float*)d_in[3];
    const float* W2    = (const float*)d_in[4];
    const float* b2    = (const float*)d_in[5];
    const float* Wl1   = (const float*)d_in[6];
    const float* bl1   = (const float*)d_in[7];
    const float* Wl2   = (const float*)d_in[8];
    const float* bl2   = (const float*)d_in[9];
    float* out = (float*)d_out;

    char* ws = (char*)d_ws;
    size_t off = 0;
    auto alloc = [&](size_t bytes) -> void* {
        void* p = ws + off;
        off += bytes;
        off = (off + 255) & ~size_t(255);
        return p;
    };
    int*   counts   = (int*)alloc(N_NODES * 4);
    int*   wofs     = (int*)alloc(N_NODES * 4);
    int*   row_ptr  = (int*)alloc((N_NODES + 1) * 4);
    float* dinv     = (float*)alloc(N_NODES * 4);
    int*   col      = (int*)alloc(N_EDGES * 4);
    float* bufA     = (float*)alloc((size_t)N_NODES * H1_D * 4);  // h1, then h2
    float* bufB     = (float*)alloc((size_t)N_NODES * H1_D * 4);  // x1, then x2
    float* partials = (float*)alloc((size_t)GEMV_BLOCKS * 100 * 4);

    // Defensive: if the harness workspace is smaller than we need, launch
    // nothing. Output stays poisoned -> clean "incorrect" report instead of
    // an OOB-store container crash. (Diagnostic either way.)
    if (off > ws_size) return;

    zero_kernel<<<(N_NODES + 255) / 256, 256, 0, stream>>>(counts, wofs, N_NODES);

    deg_kernel<<<(N_EDGES + 255) / 256, 256, 0, stream>>>(edges, counts);
    scan_kernel<<<1, 256, 0, stream>>>(counts, row_ptr);
    dinv_kernel<<<(N_NODES + 255) / 256, 256, 0, stream>>>(counts, dinv);
    fill_kernel<<<(N_EDGES + 255) / 256, 256, 0, stream>>>(edges, row_ptr, wofs, col);

    // layer 1: h1 = nodes @ W1 ; x1 = relu(agg(h1) + b1)
    gemm_kernel<F_IN_D, H1_D, 8><<<N_NODES / 8, 256, 0, stream>>>(nodes, W1, bufA);
    agg_kernel<H1_D><<<N_NODES, 256, 0, stream>>>(bufA, dinv, row_ptr, col, b1, bufB);

    // layer 2: h2 = x1 @ W2 ; x2 = relu(agg(h2) + b2)
    gemm_kernel<H1_D, H2_D, 8><<<N_NODES / 8, 256, 0, stream>>>(bufB, W2, bufA);
    agg_kernel<H2_D><<<N_NODES, 256, 0, stream>>>(bufA, dinv, row_ptr, col, b2, bufB);

    // final: y1 = relu(x2_flat @ Wl1 + bl1) ; out = sigmoid(y1 @ Wl2 + bl2)
    gemv_kernel<<<GEMV_BLOCKS, GEMV_THREADS, 0, stream>>>((const float4*)Wl1, bufB, partials);
    head_kernel<<<1, 1024, 0, stream>>>(partials, bl1, Wl2, bl2, out);
}